// Round 4
// baseline (248.147 us; speedup 1.0000x reference)
//
#include <hip/hip_runtime.h>
#include <math.h>

// ---------------- types / helpers ----------------
typedef float f32x4 __attribute__((ext_vector_type(4)));
typedef __bf16 bf16x8 __attribute__((ext_vector_type(8)));
typedef unsigned short u16x8 __attribute__((ext_vector_type(8)));
typedef unsigned short ushort_t;

#define MFMA16(a, b, c) __builtin_amdgcn_mfma_f32_16x16x32_bf16((a), (b), (c), 0, 0, 0)

static __device__ __forceinline__ ushort_t f2bf(float f) {
  union { float f; unsigned u; } v; v.f = f;
  unsigned u = v.u;
  return (ushort_t)((u + 0x7FFFu + ((u >> 16) & 1u)) >> 16);  // RNE
}
static __device__ __forceinline__ float bf2f(ushort_t h) {
  union { unsigned u; float f; } v; v.u = ((unsigned)h) << 16;
  return v.f;
}
// async global->LDS, 16B per lane; lds pointer must be wave-uniform (dest = base + lane*16)
static __device__ __forceinline__ void gl_lds16(const void* g, void* lds_uniform) {
  __builtin_amdgcn_global_load_lds(
      (const __attribute__((address_space(1))) unsigned int*)g,
      (__attribute__((address_space(3))) unsigned int*)lds_uniform, 16, 0, 0);
}

// ---------------- fused prep: RoPE table first (fp64 sincos overlaps casts) ----------
// blocks [0,512): rope table 4096*32; [512,8704): x cast; [8704,12800): 4 weights.
__global__ void prep(const float* __restrict__ x,
                     const float* __restrict__ wq, const float* __restrict__ wk,
                     const float* __restrict__ wv, const float* __restrict__ wo,
                     ushort_t* __restrict__ Xb, ushort_t* __restrict__ Wqb,
                     ushort_t* __restrict__ Wkb, ushort_t* __restrict__ Wvb,
                     ushort_t* __restrict__ Wob, float2* __restrict__ cs) {
  const int bid = blockIdx.x;
  if (bid < 512) {
    int idx = bid * 256 + threadIdx.x;  // 4096*32 entries
    int pos = idx >> 5, i = idx & 31;
    double inv = exp2(-(double)i * 0.41524101186092029);  // log2(10000)/32
    double th = (double)pos * inv;
    double s, c;
    sincos(th, &s, &c);
    cs[idx] = make_float2((float)c, (float)s);
  } else {
    const float* src;
    ushort_t* dst;
    int i;
    if (bid < 8704) {
      src = x; dst = Xb;
      i = (bid - 512) * 256 + threadIdx.x;
    } else {
      const int wi = (bid - 8704) >> 10;
      src = (wi == 0) ? wq : (wi == 1) ? wk : (wi == 2) ? wv : wo;
      dst = (wi == 0) ? Wqb : (wi == 1) ? Wkb : (wi == 2) ? Wvb : Wob;
      i = ((bid - 8704) & 1023) * 256 + threadIdx.x;
    }
    f32x4 v = ((const f32x4*)src)[i];
    ushort4 o;
    o.x = f2bf(v.x); o.y = f2bf(v.y); o.z = f2bf(v.z); o.w = f2bf(v.w);
    ((ushort4*)dst)[i] = o;
  }
}

// ---------------- NT GEMM, BK=64, XOR-swizzled LDS (R1 version: 64.3us, 0 conflicts) -
// C[m][n] = sum_k A[m][k]*W[n][k]. A: MxK bf16 rm, W: NxK bf16 rm.
template <int OUTBF>
__global__ __launch_bounds__(256) void gemm_nt(
    const ushort_t* __restrict__ A,
    const ushort_t* __restrict__ W0, const ushort_t* __restrict__ W1, const ushort_t* __restrict__ W2,
    void* __restrict__ C0, void* __restrict__ C1, void* __restrict__ C2,
    int K, int N) {
  __shared__ __align__(16) ushort_t As[128 * 64];
  __shared__ __align__(16) ushort_t Bs[128 * 64];
  const int z = blockIdx.z;
  const ushort_t* W = (z == 0) ? W0 : (z == 1 ? W1 : W2);
  void* Cv = (z == 0) ? C0 : (z == 1 ? C1 : C2);

  const int t = threadIdx.x;
  const int lane = t & 63;
  const int l15 = lane & 15;
  const int quad = lane >> 4;
  const int wave = t >> 6;
  const int wm = wave & 1, wn = wave >> 1;
  const int bm = blockIdx.x, bn = blockIdx.y;

  // staging: thread t -> row t>>3, LDS chunk t&7, global chunk (t&7)^(row&7)
  const int srow = t >> 3;
  const int schunk = (t & 7) ^ (srow & 7);
  const ushort_t* Ag = A + (size_t)(bm * 128 + srow) * K + schunk * 8;
  const ushort_t* Wg = W + (size_t)(bn * 128 + srow) * K + schunk * 8;
  char* AsB = (char*)As + (t & 192) * 16;  // wave-uniform; lane slot = base + lane*16
  char* BsB = (char*)Bs + (t & 192) * 16;
  const size_t rK = (size_t)32 * K;

  const f32x4 zero4 = {0.f, 0.f, 0.f, 0.f};
  f32x4 acc[4][4];
#pragma unroll
  for (int i = 0; i < 4; ++i)
#pragma unroll
    for (int j = 0; j < 4; ++j) acc[i][j] = zero4;

  for (int kt = 0; kt < K; kt += 64) {
#pragma unroll
    for (int p = 0; p < 4; ++p) {
      gl_lds16(Ag + p * rK + kt, AsB + p * 4096);
      gl_lds16(Wg + p * rK + kt, BsB + p * 4096);
    }
    __syncthreads();
#pragma unroll
    for (int ks = 0; ks < 2; ++ks) {
      bf16x8 af[4], bfr[4];
#pragma unroll
      for (int i = 0; i < 4; ++i) {
        const int r = wm * 64 + i * 16 + l15;
        af[i] = *(const bf16x8*)&As[r * 64 + (((ks * 4 + quad) ^ (r & 7)) * 8)];
      }
#pragma unroll
      for (int j = 0; j < 4; ++j) {
        const int r = wn * 64 + j * 16 + l15;
        bfr[j] = *(const bf16x8*)&Bs[r * 64 + (((ks * 4 + quad) ^ (r & 7)) * 8)];
      }
#pragma unroll
      for (int i = 0; i < 4; ++i)
#pragma unroll
        for (int j = 0; j < 4; ++j) acc[i][j] = MFMA16(af[i], bfr[j], acc[i][j]);
    }
    __syncthreads();
  }

  const int rbase = bm * 128 + wm * 64 + quad * 4;
  const int cbase = bn * 128 + wn * 64 + l15;
#pragma unroll
  for (int i = 0; i < 4; ++i)
#pragma unroll
    for (int j = 0; j < 4; ++j)
#pragma unroll
      for (int r = 0; r < 4; ++r) {
        size_t idx = (size_t)(rbase + i * 16 + r) * N + (cbase + j * 16);
        if (OUTBF)
          ((ushort_t*)Cv)[idx] = f2bf(acc[i][j][r]);
        else
          ((float*)Cv)[idx] = acc[i][j][r];
      }
}

// ---------------- fused windowed attention (rope applied here) ----------------
// grid = (64, 16, 2): x = win*4 + quarter, y = head, z = batch. 256 threads / 4 waves.
// Each wave: 16 q-rows x 256 keys -> S[16] f32x4 (64 regs).
// NO min-occupancy launch bound: a VGPR cap below natural demand (~130) causes
// scratch spill, and scratch allocation throttles workgroup dispatch (R1/R2: 1.3% occ).
static __device__ __forceinline__ void rope8(const ushort_t* __restrict__ g,
                                             ushort_t* __restrict__ lds,
                                             const float2* __restrict__ cs4) {
  uint4 raw = *(const uint4*)g;
  unsigned rw[4] = {raw.x, raw.y, raw.z, raw.w};
  ushort_t o[8];
#pragma unroll
  for (int m = 0; m < 4; ++m) {
    float x1 = bf2f((ushort_t)(rw[m] & 0xffffu));
    float x2 = bf2f((ushort_t)(rw[m] >> 16));
    float2 sc = cs4[m];
    o[2 * m]     = f2bf(x1 * sc.x - x2 * sc.y);
    o[2 * m + 1] = f2bf(x1 * sc.y + x2 * sc.x);
  }
  uint4 w;
  w.x = (unsigned)o[0] | ((unsigned)o[1] << 16);
  w.y = (unsigned)o[2] | ((unsigned)o[3] << 16);
  w.z = (unsigned)o[4] | ((unsigned)o[5] << 16);
  w.w = (unsigned)o[6] | ((unsigned)o[7] << 16);
  *(uint4*)lds = w;  // ds_write_b128
}

__global__ __launch_bounds__(256) void attn(
    const ushort_t* __restrict__ Qb, const ushort_t* __restrict__ Kb,
    const ushort_t* __restrict__ Vb, ushort_t* __restrict__ Yb,
    const float2* __restrict__ cs) {
  // 43008 B LDS, overlaid: phase A: Ks[256][72] @0; phase B: Vt[64][264] @0, Pc[64][72] @33792B
  __shared__ __align__(16) ushort_t smem[21504];
  ushort_t* Ks = smem;
  ushort_t* Vt = smem;
  ushort_t* Pc = smem + 16896;

  const int t = threadIdx.x;
  const int lane = t & 63, wave = t >> 6;
  const int l15 = lane & 15, quad = lane >> 4;
  const int win = blockIdx.x >> 2, qq = blockIdx.x & 3;
  const int h = blockIdx.y, b = blockIdx.z;
  const int kBase = win * 256;
  const int qRow0 = kBase + qq * 64 + wave * 16;  // this wave's first q row
  const size_t gbase = ((size_t)b * 4096) * 1024 + h * 64;

  const int sr = t >> 3;       // 0..31
  const int c0 = (t & 7) * 8;  // 0..56

  // ---- stage K with rope ----
#pragma unroll
  for (int p = 0; p < 8; ++p) {
    int r = p * 32 + sr;
    rope8(Kb + gbase + (size_t)(kBase + r) * 1024 + c0, Ks + r * 72 + c0,
          cs + (kBase + r) * 32 + (c0 >> 1));
  }
  __syncthreads();

  // ---- QK^T: S[16 q x 256 k] per wave; Q A-frags direct from global, roped in regs --
  // A-frag lane holds 8 consecutive d-cols of row qRow0+l15 -> rope pairs are lane-local.
  const f32x4 zero4 = {0.f, 0.f, 0.f, 0.f};
  f32x4 S[16];
#pragma unroll
  for (int j = 0; j < 16; ++j) S[j] = zero4;
#pragma unroll
  for (int ks = 0; ks < 2; ++ks) {
    union { u16x8 u; bf16x8 b; } aq;
    aq.u = *(const u16x8*)(Qb + gbase + (size_t)(qRow0 + l15) * 1024 + ks * 32 + quad * 8);
    const float2* csq = cs + (size_t)(qRow0 + l15) * 32 + ks * 16 + quad * 4;
#pragma unroll
    for (int m = 0; m < 4; ++m) {
      float x1 = bf2f(aq.u[2 * m]);
      float x2 = bf2f(aq.u[2 * m + 1]);
      float2 sc = csq[m];
      aq.u[2 * m]     = f2bf((x1 * sc.x - x2 * sc.y) * 0.125f);
      aq.u[2 * m + 1] = f2bf((x1 * sc.y + x2 * sc.x) * 0.125f);
    }
#pragma unroll
    for (int j = 0; j < 16; ++j) {
      bf16x8 bk = *(const bf16x8*)&Ks[(j * 16 + l15) * 72 + ks * 32 + quad * 8];
      S[j] = MFMA16(aq.b, bk, S[j]);
    }
  }

  // ---- softmax (fp32; row m = quad*4+r, cols = j*16 + l15) ----
  float linv[4];
#pragma unroll
  for (int r = 0; r < 4; ++r) {
    float mx = S[0][r];
#pragma unroll
    for (int j = 1; j < 16; ++j) mx = fmaxf(mx, S[j][r]);
    mx = fmaxf(mx, __shfl_xor(mx, 1));
    mx = fmaxf(mx, __shfl_xor(mx, 2));
    mx = fmaxf(mx, __shfl_xor(mx, 4));
    mx = fmaxf(mx, __shfl_xor(mx, 8));
    float sum = 0.f;
#pragma unroll
    for (int j = 0; j < 16; ++j) {
      float e = __expf(S[j][r] - mx);
      S[j][r] = e;
      sum += e;
    }
    sum += __shfl_xor(sum, 1);
    sum += __shfl_xor(sum, 2);
    sum += __shfl_xor(sum, 4);
    sum += __shfl_xor(sum, 8);
    linv[r] = 1.0f / sum;
  }
  __syncthreads();  // done reading Ks; overlay becomes Vt

  // ---- stage V transposed: Vt[d][k], lane-staggered (conflict-free) ----
#pragma unroll
  for (int p = 0; p < 8; ++p) {
    int k = p * 32 + sr;
    uint4 raw = *(const uint4*)(Vb + gbase + (size_t)(kBase + k) * 1024 + c0);
    ushort_t vv[8];
    vv[0] = raw.x & 0xffffu; vv[1] = raw.x >> 16;
    vv[2] = raw.y & 0xffffu; vv[3] = raw.y >> 16;
    vv[4] = raw.z & 0xffffu; vv[5] = raw.z >> 16;
    vv[6] = raw.w & 0xffffu; vv[7] = raw.w >> 16;
#pragma unroll
    for (int e = 0; e < 8; ++e) {
      int ee = (e + (t & 7)) & 7;
      Vt[(c0 + ee) * 264 + k] = vv[ee];
    }
  }
  __syncthreads();  // Vt complete; Pc is wave-private below -> no more barriers

  // ---- PV with per-wave P chunks through LDS (C-layout -> A-layout) ----
  const int qw = wave * 16;
  f32x4 O[4];
#pragma unroll
  for (int jd = 0; jd < 4; ++jd) O[jd] = zero4;

#pragma unroll
  for (int kc = 0; kc < 4; ++kc) {
#pragma unroll
    for (int jj = 0; jj < 4; ++jj) {
      int j = kc * 4 + jj;
#pragma unroll
      for (int r = 0; r < 4; ++r)
        Pc[(qw + quad * 4 + r) * 72 + jj * 16 + l15] = f2bf(S[j][r]);
    }
#pragma unroll
    for (int ks = 0; ks < 2; ++ks) {
      bf16x8 a = *(const bf16x8*)&Pc[(qw + l15) * 72 + ks * 32 + quad * 8];
#pragma unroll
      for (int jd = 0; jd < 4; ++jd) {
        bf16x8 bv = *(const bf16x8*)&Vt[(jd * 16 + l15) * 264 + kc * 64 + ks * 32 + quad * 8];
        O[jd] = MFMA16(a, bv, O[jd]);
      }
    }
  }

  // ---- epilogue: normalize, write Y (B,T,C) bf16 ----
#pragma unroll
  for (int jd = 0; jd < 4; ++jd)
#pragma unroll
    for (int r = 0; r < 4; ++r) {
      int row = qRow0 + quad * 4 + r;
      Yb[gbase + (size_t)row * 1024 + jd * 16 + l15] = f2bf(O[jd][r] * linv[r]);
    }
}

// ---------------- launch ----------------
extern "C" void kernel_launch(void* const* d_in, const int* in_sizes, int n_in,
                              void* d_out, int out_size, void* d_ws, size_t ws_size,
                              hipStream_t stream) {
  (void)in_sizes; (void)n_in; (void)out_size; (void)ws_size;
  const float* x  = (const float*)d_in[0];
  const float* wq = (const float*)d_in[1];
  const float* wk = (const float*)d_in[2];
  const float* wv = (const float*)d_in[3];
  const float* wo = (const float*)d_in[4];

  char* ws = (char*)d_ws;
  // workspace layout (bytes): Xb 16M | Wq..Wo 4x2M | Qb 16M | Kb 16M | Vb 16M | Yb 16M | cs 1M
  ushort_t* Xb  = (ushort_t*)(ws);
  ushort_t* Wqb = (ushort_t*)(ws + 16777216);
  ushort_t* Wkb = Wqb + 1048576;
  ushort_t* Wvb = Wkb + 1048576;
  ushort_t* Wob = Wvb + 1048576;
  ushort_t* Qb  = (ushort_t*)(ws + 25165824);
  ushort_t* Kb  = Qb + 8388608;
  ushort_t* Vb  = Kb + 8388608;
  ushort_t* Yb  = Vb + 8388608;
  float2*   cs  = (float2*)(ws + 92274688);

  prep<<<dim3(12800), dim3(256), 0, stream>>>(x, wq, wk, wv, wo,
                                              Xb, Wqb, Wkb, Wvb, Wob, cs);

  gemm_nt<1><<<dim3(64, 8, 3), dim3(256), 0, stream>>>(
      Xb, Wqb, Wkb, Wvb, (void*)Qb, (void*)Kb, (void*)Vb, 1024, 1024);

  attn<<<dim3(64, 16, 2), dim3(256), 0, stream>>>(Qb, Kb, Vb, Yb, cs);

  gemm_nt<0><<<dim3(64, 8, 1), dim3(256), 0, stream>>>(
      Yb, Wob, Wob, Wob, d_out, d_out, d_out, 1024, 1024);
}

// Round 5
// 231.546 us; speedup vs baseline: 1.0717x; 1.0717x over previous
//
#include <hip/hip_runtime.h>
#include <math.h>

// ---------------- types / helpers ----------------
typedef float f32x4 __attribute__((ext_vector_type(4)));
typedef __bf16 bf16x8 __attribute__((ext_vector_type(8)));
typedef _Float16 f16x4 __attribute__((ext_vector_type(4)));
typedef unsigned short ushort_t;

#define MFMA16(a, b, c) __builtin_amdgcn_mfma_f32_16x16x32_bf16((a), (b), (c), 0, 0, 0)
#define MFMAPV(a, b, c) __builtin_amdgcn_mfma_f32_16x16x16f16((a), (b), (c), 0, 0, 0)

static __device__ __forceinline__ ushort_t f2bf(float f) {
  union { float f; unsigned u; } v; v.f = f;
  unsigned u = v.u;
  return (ushort_t)((u + 0x7FFFu + ((u >> 16) & 1u)) >> 16);  // RNE
}
static __device__ __forceinline__ float bf2f(ushort_t h) {
  union { unsigned u; float f; } v; v.u = ((unsigned)h) << 16;
  return v.f;
}
// async global->LDS, 16B per lane; lds dest = wave-uniform base + lane*16
static __device__ __forceinline__ void gl_lds16(const void* g, void* lds_uniform) {
  __builtin_amdgcn_global_load_lds(
      (const __attribute__((address_space(1))) unsigned int*)g,
      (__attribute__((address_space(3))) unsigned int*)lds_uniform, 16, 0, 0);
}

// ---------------- fused prep: RoPE table + casts ----------
// blocks [0,512): rope table 4096*32; [512,8704): x cast; [8704,12800): 4 weights.
__global__ void prep(const float* __restrict__ x,
                     const float* __restrict__ wq, const float* __restrict__ wk,
                     const float* __restrict__ wv, const float* __restrict__ wo,
                     ushort_t* __restrict__ Xb, ushort_t* __restrict__ Wqb,
                     ushort_t* __restrict__ Wkb, ushort_t* __restrict__ Wvb,
                     ushort_t* __restrict__ Wob, float2* __restrict__ cs) {
  const int bid = blockIdx.x;
  if (bid < 512) {
    int idx = bid * 256 + threadIdx.x;  // 4096*32 entries
    int pos = idx >> 5, i = idx & 31;
    double inv = exp2(-(double)i * 0.41524101186092029);  // log2(10000)/32
    double th = (double)pos * inv;
    double s, c;
    sincos(th, &s, &c);
    cs[idx] = make_float2((float)c, (float)s);
  } else {
    const float* src;
    ushort_t* dst;
    int i;
    if (bid < 8704) {
      src = x; dst = Xb;
      i = (bid - 512) * 256 + threadIdx.x;
    } else {
      const int wi = (bid - 8704) >> 10;
      src = (wi == 0) ? wq : (wi == 1) ? wk : (wi == 2) ? wv : wo;
      dst = (wi == 0) ? Wqb : (wi == 1) ? Wkb : (wi == 2) ? Wvb : Wob;
      i = ((bid - 8704) & 1023) * 256 + threadIdx.x;
    }
    f32x4 v = ((const f32x4*)src)[i];
    ushort4 o;
    o.x = f2bf(v.x); o.y = f2bf(v.y); o.z = f2bf(v.z); o.w = f2bf(v.w);
    ((ushort4*)dst)[i] = o;
  }
}

// ---------------- NT GEMM, BK=64, XOR-swizzled LDS ----------------
// C[m][n] = sum_k A[m][k]*W[n][k]. MODE 0: f32 out. MODE 1: bf16 out (z<2), fp16 out (z==2).
template <int MODE>
__global__ __launch_bounds__(256) void gemm_nt(
    const ushort_t* __restrict__ A,
    const ushort_t* __restrict__ W0, const ushort_t* __restrict__ W1, const ushort_t* __restrict__ W2,
    void* __restrict__ C0, void* __restrict__ C1, void* __restrict__ C2,
    int K, int N) {
  __shared__ __align__(16) ushort_t As[128 * 64];
  __shared__ __align__(16) ushort_t Bs[128 * 64];
  const int z = blockIdx.z;
  const ushort_t* W = (z == 0) ? W0 : (z == 1 ? W1 : W2);
  void* Cv = (z == 0) ? C0 : (z == 1 ? C1 : C2);

  const int t = threadIdx.x;
  const int lane = t & 63;
  const int l15 = lane & 15;
  const int quad = lane >> 4;
  const int wave = t >> 6;
  const int wm = wave & 1, wn = wave >> 1;
  const int bm = blockIdx.x, bn = blockIdx.y;

  const int srow = t >> 3;
  const int schunk = (t & 7) ^ (srow & 7);
  const ushort_t* Ag = A + (size_t)(bm * 128 + srow) * K + schunk * 8;
  const ushort_t* Wg = W + (size_t)(bn * 128 + srow) * K + schunk * 8;
  char* AsB = (char*)As + (t & 192) * 16;
  char* BsB = (char*)Bs + (t & 192) * 16;
  const size_t rK = (size_t)32 * K;

  const f32x4 zero4 = {0.f, 0.f, 0.f, 0.f};
  f32x4 acc[4][4];
#pragma unroll
  for (int i = 0; i < 4; ++i)
#pragma unroll
    for (int j = 0; j < 4; ++j) acc[i][j] = zero4;

  for (int kt = 0; kt < K; kt += 64) {
#pragma unroll
    for (int p = 0; p < 4; ++p) {
      gl_lds16(Ag + p * rK + kt, AsB + p * 4096);
      gl_lds16(Wg + p * rK + kt, BsB + p * 4096);
    }
    __syncthreads();
#pragma unroll
    for (int ks = 0; ks < 2; ++ks) {
      bf16x8 af[4], bfr[4];
#pragma unroll
      for (int i = 0; i < 4; ++i) {
        const int r = wm * 64 + i * 16 + l15;
        af[i] = *(const bf16x8*)&As[r * 64 + (((ks * 4 + quad) ^ (r & 7)) * 8)];
      }
#pragma unroll
      for (int j = 0; j < 4; ++j) {
        const int r = wn * 64 + j * 16 + l15;
        bfr[j] = *(const bf16x8*)&Bs[r * 64 + (((ks * 4 + quad) ^ (r & 7)) * 8)];
      }
#pragma unroll
      for (int i = 0; i < 4; ++i)
#pragma unroll
        for (int j = 0; j < 4; ++j) acc[i][j] = MFMA16(af[i], bfr[j], acc[i][j]);
    }
    __syncthreads();
  }

  const int rbase = bm * 128 + wm * 64 + quad * 4;
  const int cbase = bn * 128 + wn * 64 + l15;
#pragma unroll
  for (int i = 0; i < 4; ++i)
#pragma unroll
    for (int j = 0; j < 4; ++j)
#pragma unroll
      for (int r = 0; r < 4; ++r) {
        size_t idx = (size_t)(rbase + i * 16 + r) * N + (cbase + j * 16);
        if (MODE == 0) {
          ((float*)Cv)[idx] = acc[i][j][r];
        } else if (z == 2) {  // V: store fp16 (PV runs on f16 MFMA)
          union { _Float16 h; ushort_t u; } cv;
          cv.h = (_Float16)acc[i][j][r];
          ((ushort_t*)Cv)[idx] = cv.u;
        } else {
          ((ushort_t*)Cv)[idx] = f2bf(acc[i][j][r]);
        }
      }
}

// ---------------- rope prepass: in-place RoPE on Q (x0.125) and K ----------------
// 2048 blocks x 256; each thread 2 uint4 of Q + 2 of K (8M bf16 each tensor).
static __device__ __forceinline__ uint4 rope_u4(uint4 raw, const float2* __restrict__ c4,
                                                float scale) {
  unsigned rw[4] = {raw.x, raw.y, raw.z, raw.w};
  ushort_t o[8];
#pragma unroll
  for (int m = 0; m < 4; ++m) {
    float x1 = bf2f((ushort_t)(rw[m] & 0xffffu));
    float x2 = bf2f((ushort_t)(rw[m] >> 16));
    float2 sc = c4[m];
    o[2 * m]     = f2bf((x1 * sc.x - x2 * sc.y) * scale);
    o[2 * m + 1] = f2bf((x1 * sc.y + x2 * sc.x) * scale);
  }
  uint4 w;
  w.x = (unsigned)o[0] | ((unsigned)o[1] << 16);
  w.y = (unsigned)o[2] | ((unsigned)o[3] << 16);
  w.z = (unsigned)o[4] | ((unsigned)o[5] << 16);
  w.w = (unsigned)o[6] | ((unsigned)o[7] << 16);
  return w;
}

__global__ void ropeqk(ushort_t* __restrict__ Qb, ushort_t* __restrict__ Kb,
                       const float2* __restrict__ cs) {
  const int idx0 = blockIdx.x * 256 + threadIdx.x;
#pragma unroll
  for (int g = 0; g < 2; ++g) {
    const int idx = idx0 + g * 524288;        // uint4 index, 1M per tensor
    const int row = idx >> 7;                  // 128 uint4 per 1024-el row
    const int col8 = (idx & 127) << 3;
    const float2* c4 = cs + (((size_t)(row & 4095)) << 5) + ((col8 & 63) >> 1);
    uint4 q = ((const uint4*)Qb)[idx];
    uint4 k = ((const uint4*)Kb)[idx];
    ((uint4*)Qb)[idx] = rope_u4(q, c4, 0.125f);
    ((uint4*)Kb)[idx] = rope_u4(k, c4, 1.0f);
  }
}

// ---------------- fused windowed attention (S^T trick, pre-roped Q/K, fp16 V) --------
// grid 2048: bx = qq*512 + ((b*16+h)*16+win)  (same-window blocks 512 apart -> same XCD).
// 256 threads / 4 waves; wave handles 16 q-rows x 256 keys.
// QK^T computed transposed: S^T = MFMA(A=K, B=Q) -> C-layout row k=quad*4+r, col q=l15.
// That C-layout IS the B-operand layout of mfma_f32_16x16x16_f16, so P-frags for PV are a
// pure in-register convertvector (no LDS transform). O^T output col is also q=l15 -> fold
// 1/sum into epilogue. LDS: phase A Ks[256][64] swizzled 32KB (DMA); phase B Vt[64][264]
// 33792B (overlaid); epilogue: per-wave 16x72 transpose tiles (overlaid in Vt).
__global__ __launch_bounds__(256) void attn(
    const ushort_t* __restrict__ Qb, const ushort_t* __restrict__ Kb,
    const ushort_t* __restrict__ Vb, ushort_t* __restrict__ Yb) {
  __shared__ __align__(16) ushort_t smem[16896];  // 33792 B
  ushort_t* Ks = smem;
  ushort_t* Vt = smem;

  const int t = threadIdx.x;
  const int lane = t & 63, wave = t >> 6;
  const int l15 = lane & 15, quad = lane >> 4;
  const int qq = blockIdx.x >> 9;
  const int s = blockIdx.x & 511;
  const int win = s & 15, h = (s >> 4) & 15, b = s >> 8;
  const int kBase = win * 256;
  const int qRow0 = kBase + qq * 64 + wave * 16;
  const size_t gbase = ((size_t)b * 4096) * 1024 + h * 64;

  const int sr = t >> 3;       // 0..31
  const int c0 = (t & 7) * 8;  // 0..56

  // ---- stage K via async DMA, XOR-swizzled [256][64] ----
  const int schunk = ((t & 7) ^ (sr & 7)) * 8;
  const ushort_t* Kg = Kb + gbase + (size_t)(kBase + sr) * 1024 + schunk;
  char* LdsB = (char*)smem + (t & 192) * 16;
#pragma unroll
  for (int p = 0; p < 8; ++p) gl_lds16(Kg + (size_t)p * 32 * 1024, LdsB + p * 4096);

  // ---- Q B-frags direct from global (pre-roped, pre-scaled) ----
  bf16x8 qf[2];
#pragma unroll
  for (int ks = 0; ks < 2; ++ks)
    qf[ks] = *(const bf16x8*)(Qb + gbase + (size_t)(qRow0 + l15) * 1024 + ks * 32 + quad * 8);

  __syncthreads();  // #1: K DMA complete (implies vmcnt drain)

  // ---- S^T = K·Q^T : rows k = j*16+quad*4+r, col q = l15 ----
  const f32x4 zero4 = {0.f, 0.f, 0.f, 0.f};
  f32x4 S[16];
#pragma unroll
  for (int j = 0; j < 16; ++j) S[j] = zero4;
#pragma unroll
  for (int ks = 0; ks < 2; ++ks)
#pragma unroll
    for (int j = 0; j < 16; ++j) {
      bf16x8 kf = *(const bf16x8*)&Ks[(j * 16 + l15) * 64 + ((ks * 4 + quad) ^ (l15 & 7)) * 8];
      S[j] = MFMA16(kf, qf[ks], S[j]);
    }

  // ---- softmax: one (max,sum) per lane (column q = l15); quads combined via shfl ----
  float mx = S[0][0];
#pragma unroll
  for (int j = 0; j < 16; ++j)
#pragma unroll
    for (int e = 0; e < 4; ++e) mx = fmaxf(mx, S[j][e]);
  mx = fmaxf(mx, __shfl_xor(mx, 16));
  mx = fmaxf(mx, __shfl_xor(mx, 32));
  float sum = 0.f;
#pragma unroll
  for (int j = 0; j < 16; ++j)
#pragma unroll
    for (int e = 0; e < 4; ++e) {
      float e_ = __expf(S[j][e] - mx);
      S[j][e] = e_;
      sum += e_;
    }
  sum += __shfl_xor(sum, 16);
  sum += __shfl_xor(sum, 32);
  const float linv = 1.0f / sum;

  // ---- P frags: C-layout == f16-MFMA B-operand layout -> pure register cvt ----
  f16x4 pf[16];
#pragma unroll
  for (int j = 0; j < 16; ++j) pf[j] = __builtin_convertvector(S[j], f16x4);

  // ---- V loads (fp16 bits, opaque) ----
  uint4 vraw[8];
#pragma unroll
  for (int p = 0; p < 8; ++p)
    vraw[p] = *(const uint4*)(Vb + gbase + (size_t)(kBase + p * 32 + sr) * 1024 + c0);

  __syncthreads();  // #2: all Ks reads done; region becomes Vt

  // ---- stage V transposed Vt[d][k], lane-staggered stores (conflict-free) ----
#pragma unroll
  for (int p = 0; p < 8; ++p) {
    const int k = p * 32 + sr;
    ushort_t vv[8];
    vv[0] = vraw[p].x & 0xffffu; vv[1] = vraw[p].x >> 16;
    vv[2] = vraw[p].y & 0xffffu; vv[3] = vraw[p].y >> 16;
    vv[4] = vraw[p].z & 0xffffu; vv[5] = vraw[p].z >> 16;
    vv[6] = vraw[p].w & 0xffffu; vv[7] = vraw[p].w >> 16;
#pragma unroll
    for (int e = 0; e < 8; ++e) {
      const int ee = (e + (t & 7)) & 7;
      Vt[(c0 + ee) * 264 + k] = vv[ee];
    }
  }
  __syncthreads();  // #3: Vt complete

  // ---- O^T[d][q] = sum_k V^T[d][k] P[q][k] via f16 16x16x16 MFMA ----
  f32x4 O[4];
#pragma unroll
  for (int jd = 0; jd < 4; ++jd) O[jd] = zero4;
#pragma unroll
  for (int j = 0; j < 16; ++j)
#pragma unroll
    for (int jd = 0; jd < 4; ++jd) {
      f16x4 vf = *(const f16x4*)&Vt[(jd * 16 + l15) * 264 + j * 16 + quad * 4];
      O[jd] = MFMAPV(vf, pf[j], O[jd]);
    }

  __syncthreads();  // #4: all Vt reads done; region becomes per-wave transpose tiles

  // ---- epilogue: per-wave 16x72 tile transpose -> coalesced 128B row writes ----
  ushort_t* tile = smem + wave * 1152;  // 16 rows x 72 (pitch 144B, 16B-aligned)
#pragma unroll
  for (int jd = 0; jd < 4; ++jd)
#pragma unroll
    for (int r = 0; r < 4; ++r)
      tile[l15 * 72 + jd * 16 + quad * 4 + r] = f2bf(O[jd][r] * linv);
  // wave-private: compiler inserts lgkmcnt wait; no barrier needed
#pragma unroll
  for (int g = 0; g < 2; ++g) {
    uint4 w = *(const uint4*)&tile[l15 * 72 + quad * 16 + g * 8];
    *(uint4*)(Yb + gbase + (size_t)(qRow0 + l15) * 1024 + quad * 16 + g * 8) = w;
  }
}

// ---------------- launch ----------------
extern "C" void kernel_launch(void* const* d_in, const int* in_sizes, int n_in,
                              void* d_out, int out_size, void* d_ws, size_t ws_size,
                              hipStream_t stream) {
  (void)in_sizes; (void)n_in; (void)out_size; (void)ws_size;
  const float* x  = (const float*)d_in[0];
  const float* wq = (const float*)d_in[1];
  const float* wk = (const float*)d_in[2];
  const float* wv = (const float*)d_in[3];
  const float* wo = (const float*)d_in[4];

  char* ws = (char*)d_ws;
  // workspace layout (bytes): Xb 16M | Wq..Wo 4x2M | Qb 16M | Kb 16M | Vb(fp16) 16M | Yb 16M | cs 1M
  ushort_t* Xb  = (ushort_t*)(ws);
  ushort_t* Wqb = (ushort_t*)(ws + 16777216);
  ushort_t* Wkb = Wqb + 1048576;
  ushort_t* Wvb = Wkb + 1048576;
  ushort_t* Wob = Wvb + 1048576;
  ushort_t* Qb  = (ushort_t*)(ws + 25165824);
  ushort_t* Kb  = Qb + 8388608;
  ushort_t* Vb  = Kb + 8388608;
  ushort_t* Yb  = Vb + 8388608;
  float2*   cs  = (float2*)(ws + 92274688);

  prep<<<dim3(12800), dim3(256), 0, stream>>>(x, wq, wk, wv, wo,
                                              Xb, Wqb, Wkb, Wvb, Wob, cs);

  gemm_nt<1><<<dim3(64, 8, 3), dim3(256), 0, stream>>>(
      Xb, Wqb, Wkb, Wvb, (void*)Qb, (void*)Kb, (void*)Vb, 1024, 1024);

  ropeqk<<<dim3(2048), dim3(256), 0, stream>>>(Qb, Kb, cs);

  attn<<<dim3(2048), dim3(256), 0, stream>>>(Qb, Kb, Vb, Yb);

  gemm_nt<0><<<dim3(64, 8, 1), dim3(256), 0, stream>>>(
      Yb, Wob, Wob, Wob, d_out, d_out, d_out, 1024, 1024);
}

// Round 6
// 230.280 us; speedup vs baseline: 1.0776x; 1.0055x over previous
//
#include <hip/hip_runtime.h>
#include <math.h>

// ---------------- types / helpers ----------------
typedef float f32x4 __attribute__((ext_vector_type(4)));
typedef __bf16 bf16x8 __attribute__((ext_vector_type(8)));
typedef _Float16 f16x4 __attribute__((ext_vector_type(4)));
typedef unsigned short u16x8 __attribute__((ext_vector_type(8)));
typedef unsigned short ushort_t;

#define MFMA16(a, b, c) __builtin_amdgcn_mfma_f32_16x16x32_bf16((a), (b), (c), 0, 0, 0)
#define MFMAPV(a, b, c) __builtin_amdgcn_mfma_f32_16x16x16f16((a), (b), (c), 0, 0, 0)

static __device__ __forceinline__ ushort_t f2bf(float f) {
  union { float f; unsigned u; } v; v.f = f;
  unsigned u = v.u;
  return (ushort_t)((u + 0x7FFFu + ((u >> 16) & 1u)) >> 16);  // RNE
}
static __device__ __forceinline__ float bf2f(ushort_t h) {
  union { unsigned u; float f; } v; v.u = ((unsigned)h) << 16;
  return v.f;
}
static __device__ __forceinline__ ushort_t f2h_bits(float f) {
  union { _Float16 h; ushort_t u; } v;
  v.h = (_Float16)f;
  return v.u;
}
// async global->LDS, 16B per lane; lds dest = wave-uniform base + lane*16
static __device__ __forceinline__ void gl_lds16(const void* g, void* lds_uniform) {
  __builtin_amdgcn_global_load_lds(
      (const __attribute__((address_space(1))) unsigned int*)g,
      (__attribute__((address_space(3))) unsigned int*)lds_uniform, 16, 0, 0);
}

// ---------------- fused prep: RoPE table + casts ----------
// blocks [0,512): rope table 4096*32; [512,8704): x cast; [8704,12800): 4 weights.
__global__ void prep(const float* __restrict__ x,
                     const float* __restrict__ wq, const float* __restrict__ wk,
                     const float* __restrict__ wv, const float* __restrict__ wo,
                     ushort_t* __restrict__ Xb, ushort_t* __restrict__ Wqb,
                     ushort_t* __restrict__ Wkb, ushort_t* __restrict__ Wvb,
                     ushort_t* __restrict__ Wob, float2* __restrict__ cs) {
  const int bid = blockIdx.x;
  if (bid < 512) {
    int idx = bid * 256 + threadIdx.x;  // 4096*32 entries
    int pos = idx >> 5, i = idx & 31;
    double inv = exp2(-(double)i * 0.41524101186092029);  // log2(10000)/32
    double th = (double)pos * inv;
    double s, c;
    sincos(th, &s, &c);
    cs[idx] = make_float2((float)c, (float)s);
  } else {
    const float* src;
    ushort_t* dst;
    int i;
    if (bid < 8704) {
      src = x; dst = Xb;
      i = (bid - 512) * 256 + threadIdx.x;
    } else {
      const int wi = (bid - 8704) >> 10;
      src = (wi == 0) ? wq : (wi == 1) ? wk : (wi == 2) ? wv : wo;
      dst = (wi == 0) ? Wqb : (wi == 1) ? Wkb : (wi == 2) ? Wvb : Wob;
      i = ((bid - 8704) & 1023) * 256 + threadIdx.x;
    }
    f32x4 v = ((const f32x4*)src)[i];
    ushort4 o;
    o.x = f2bf(v.x); o.y = f2bf(v.y); o.z = f2bf(v.z); o.w = f2bf(v.w);
    ((ushort4*)dst)[i] = o;
  }
}

// ---------------- NT GEMM, BK=64, XOR-swizzled LDS (exact R1 config: 64.3us) ---------
// C[m][n] = sum_k A[m][k]*W[n][k]. A: MxK bf16 rm, W: NxK bf16 rm.
template <int OUTBF>
__global__ __launch_bounds__(256) void gemm_nt(
    const ushort_t* __restrict__ A,
    const ushort_t* __restrict__ W0, const ushort_t* __restrict__ W1, const ushort_t* __restrict__ W2,
    void* __restrict__ C0, void* __restrict__ C1, void* __restrict__ C2,
    int K, int N) {
  __shared__ __align__(16) ushort_t As[128 * 64];
  __shared__ __align__(16) ushort_t Bs[128 * 64];
  const int z = blockIdx.z;
  const ushort_t* W = (z == 0) ? W0 : (z == 1 ? W1 : W2);
  void* Cv = (z == 0) ? C0 : (z == 1 ? C1 : C2);

  const int t = threadIdx.x;
  const int lane = t & 63;
  const int l15 = lane & 15;
  const int quad = lane >> 4;
  const int wave = t >> 6;
  const int wm = wave & 1, wn = wave >> 1;
  const int bm = blockIdx.x, bn = blockIdx.y;

  const int srow = t >> 3;
  const int schunk = (t & 7) ^ (srow & 7);
  const ushort_t* Ag = A + (size_t)(bm * 128 + srow) * K + schunk * 8;
  const ushort_t* Wg = W + (size_t)(bn * 128 + srow) * K + schunk * 8;
  char* AsB = (char*)As + (t & 192) * 16;
  char* BsB = (char*)Bs + (t & 192) * 16;
  const size_t rK = (size_t)32 * K;

  const f32x4 zero4 = {0.f, 0.f, 0.f, 0.f};
  f32x4 acc[4][4];
#pragma unroll
  for (int i = 0; i < 4; ++i)
#pragma unroll
    for (int j = 0; j < 4; ++j) acc[i][j] = zero4;

  for (int kt = 0; kt < K; kt += 64) {
#pragma unroll
    for (int p = 0; p < 4; ++p) {
      gl_lds16(Ag + p * rK + kt, AsB + p * 4096);
      gl_lds16(Wg + p * rK + kt, BsB + p * 4096);
    }
    __syncthreads();
#pragma unroll
    for (int ks = 0; ks < 2; ++ks) {
      bf16x8 af[4], bfr[4];
#pragma unroll
      for (int i = 0; i < 4; ++i) {
        const int r = wm * 64 + i * 16 + l15;
        af[i] = *(const bf16x8*)&As[r * 64 + (((ks * 4 + quad) ^ (r & 7)) * 8)];
      }
#pragma unroll
      for (int j = 0; j < 4; ++j) {
        const int r = wn * 64 + j * 16 + l15;
        bfr[j] = *(const bf16x8*)&Bs[r * 64 + (((ks * 4 + quad) ^ (r & 7)) * 8)];
      }
#pragma unroll
      for (int i = 0; i < 4; ++i)
#pragma unroll
        for (int j = 0; j < 4; ++j) acc[i][j] = MFMA16(af[i], bfr[j], acc[i][j]);
    }
    __syncthreads();
  }

  const int rbase = bm * 128 + wm * 64 + quad * 4;
  const int cbase = bn * 128 + wn * 64 + l15;
#pragma unroll
  for (int i = 0; i < 4; ++i)
#pragma unroll
    for (int j = 0; j < 4; ++j)
#pragma unroll
      for (int r = 0; r < 4; ++r) {
        size_t idx = (size_t)(rbase + i * 16 + r) * N + (cbase + j * 16);
        if (OUTBF)
          ((ushort_t*)Cv)[idx] = f2bf(acc[i][j][r]);
        else
          ((float*)Cv)[idx] = acc[i][j][r];
      }
}

// ---------------- fused windowed attention (S^T trick, rope fused, bf16 V in) --------
// grid 2048: bx = qq*512 + ((b*16+h)*16+win)  (same-window blocks 512 apart -> same XCD).
// 256 threads / 4 waves; wave handles 16 q-rows x 256 keys.
// S^T = MFMA(A=K, B=Q): C-layout row k=quad*4+r, col q=l15. That C-layout IS the
// B-operand layout of mfma_f32_16x16x16_f16 -> P frags are a pure register convert.
// O^T col is also q=l15 -> 1/sum folds into epilogue. K roped during LDS staging,
// Q roped in regs (B-frag lane holds 8 consecutive d-cols -> pairs lane-local).
// V (bf16) converted to fp16 during the transpose staging.
static __device__ __forceinline__ void rope8(const ushort_t* __restrict__ g,
                                             ushort_t* __restrict__ lds,
                                             const float2* __restrict__ cs4) {
  uint4 raw = *(const uint4*)g;
  unsigned rw[4] = {raw.x, raw.y, raw.z, raw.w};
  ushort_t o[8];
#pragma unroll
  for (int m = 0; m < 4; ++m) {
    float x1 = bf2f((ushort_t)(rw[m] & 0xffffu));
    float x2 = bf2f((ushort_t)(rw[m] >> 16));
    float2 sc = cs4[m];
    o[2 * m]     = f2bf(x1 * sc.x - x2 * sc.y);
    o[2 * m + 1] = f2bf(x1 * sc.y + x2 * sc.x);
  }
  uint4 w;
  w.x = (unsigned)o[0] | ((unsigned)o[1] << 16);
  w.y = (unsigned)o[2] | ((unsigned)o[3] << 16);
  w.z = (unsigned)o[4] | ((unsigned)o[5] << 16);
  w.w = (unsigned)o[6] | ((unsigned)o[7] << 16);
  *(uint4*)lds = w;  // ds_write_b128
}

__global__ __launch_bounds__(256) void attn(
    const ushort_t* __restrict__ Qb, const ushort_t* __restrict__ Kb,
    const ushort_t* __restrict__ Vb, ushort_t* __restrict__ Yb,
    const float2* __restrict__ cs) {
  // 36864 B LDS, overlaid: phase A Ks[256][72]; phase B Vt[64][264] (33792 B);
  // phase C per-wave 16x72 transpose tiles (9216 B).
  __shared__ __align__(16) ushort_t smem[18432];
  ushort_t* Ks = smem;
  ushort_t* Vt = smem;

  const int t = threadIdx.x;
  const int lane = t & 63, wave = t >> 6;
  const int l15 = lane & 15, quad = lane >> 4;
  const int qq = blockIdx.x >> 9;
  const int s = blockIdx.x & 511;
  const int win = s & 15, h = (s >> 4) & 15, b = s >> 8;
  const int kBase = win * 256;
  const int qRow0 = kBase + qq * 64 + wave * 16;
  const size_t gbase = ((size_t)b * 4096) * 1024 + h * 64;

  const int sr = t >> 3;       // 0..31
  const int c0 = (t & 7) * 8;  // 0..56

  // ---- stage K with rope, padded [256][72] ----
#pragma unroll
  for (int p = 0; p < 8; ++p) {
    int r = p * 32 + sr;
    rope8(Kb + gbase + (size_t)(kBase + r) * 1024 + c0, Ks + r * 72 + c0,
          cs + (kBase + r) * 32 + (c0 >> 1));
  }

  // ---- Q B-frags from global, roped + scaled in regs (pairs lane-local) ----
  bf16x8 qf[2];
#pragma unroll
  for (int ks = 0; ks < 2; ++ks) {
    union { u16x8 u; bf16x8 b; } aq;
    aq.u = *(const u16x8*)(Qb + gbase + (size_t)(qRow0 + l15) * 1024 + ks * 32 + quad * 8);
    const float2* csq = cs + (size_t)((qRow0 + l15) & 4095) * 32 + ks * 16 + quad * 4;
#pragma unroll
    for (int m = 0; m < 4; ++m) {
      float x1 = bf2f(aq.u[2 * m]);
      float x2 = bf2f(aq.u[2 * m + 1]);
      float2 sc = csq[m];
      aq.u[2 * m]     = f2bf((x1 * sc.x - x2 * sc.y) * 0.125f);
      aq.u[2 * m + 1] = f2bf((x1 * sc.y + x2 * sc.x) * 0.125f);
    }
    qf[ks] = aq.b;
  }

  __syncthreads();  // #1: Ks staged

  // ---- S^T = K·Q^T : rows k = j*16+quad*4+r, col q = l15 ----
  const f32x4 zero4 = {0.f, 0.f, 0.f, 0.f};
  f32x4 S[16];
#pragma unroll
  for (int j = 0; j < 16; ++j) S[j] = zero4;
#pragma unroll
  for (int ks = 0; ks < 2; ++ks)
#pragma unroll
    for (int j = 0; j < 16; ++j) {
      bf16x8 kf = *(const bf16x8*)&Ks[(j * 16 + l15) * 72 + ks * 32 + quad * 8];
      S[j] = MFMA16(kf, qf[ks], S[j]);
    }

  // ---- softmax: one (max,sum) per lane (column q = l15); quads combined via shfl ----
  float mx = S[0][0];
#pragma unroll
  for (int j = 0; j < 16; ++j)
#pragma unroll
    for (int e = 0; e < 4; ++e) mx = fmaxf(mx, S[j][e]);
  mx = fmaxf(mx, __shfl_xor(mx, 16));
  mx = fmaxf(mx, __shfl_xor(mx, 32));
  float sum = 0.f;
#pragma unroll
  for (int j = 0; j < 16; ++j)
#pragma unroll
    for (int e = 0; e < 4; ++e) {
      float e_ = __expf(S[j][e] - mx);
      S[j][e] = e_;
      sum += e_;
    }
  sum += __shfl_xor(sum, 16);
  sum += __shfl_xor(sum, 32);
  const float linv = 1.0f / sum;

  // ---- P frags: C-layout == f16-MFMA B-operand layout -> pure register cvt ----
  f16x4 pf[16];
#pragma unroll
  for (int j = 0; j < 16; ++j) pf[j] = __builtin_convertvector(S[j], f16x4);

  // ---- V loads (bf16), hoisted to overlap latency ----
  uint4 vraw[8];
#pragma unroll
  for (int p = 0; p < 8; ++p)
    vraw[p] = *(const uint4*)(Vb + gbase + (size_t)(kBase + p * 32 + sr) * 1024 + c0);

  __syncthreads();  // #2: all Ks reads done; region becomes Vt

  // ---- stage V transposed Vt[d][k] as fp16, lane-staggered stores ----
#pragma unroll
  for (int p = 0; p < 8; ++p) {
    const int k = p * 32 + sr;
    ushort_t vv[8];
    vv[0] = f2h_bits(bf2f((ushort_t)(vraw[p].x & 0xffffu)));
    vv[1] = f2h_bits(bf2f((ushort_t)(vraw[p].x >> 16)));
    vv[2] = f2h_bits(bf2f((ushort_t)(vraw[p].y & 0xffffu)));
    vv[3] = f2h_bits(bf2f((ushort_t)(vraw[p].y >> 16)));
    vv[4] = f2h_bits(bf2f((ushort_t)(vraw[p].z & 0xffffu)));
    vv[5] = f2h_bits(bf2f((ushort_t)(vraw[p].z >> 16)));
    vv[6] = f2h_bits(bf2f((ushort_t)(vraw[p].w & 0xffffu)));
    vv[7] = f2h_bits(bf2f((ushort_t)(vraw[p].w >> 16)));
#pragma unroll
    for (int e = 0; e < 8; ++e) {
      const int ee = (e + (t & 7)) & 7;
      Vt[(c0 + ee) * 264 + k] = vv[ee];
    }
  }
  __syncthreads();  // #3: Vt complete

  // ---- O^T[d][q] = sum_k V^T[d][k] P[q][k] via f16 16x16x16 MFMA ----
  f32x4 O[4];
#pragma unroll
  for (int jd = 0; jd < 4; ++jd) O[jd] = zero4;
#pragma unroll
  for (int j = 0; j < 16; ++j)
#pragma unroll
    for (int jd = 0; jd < 4; ++jd) {
      f16x4 vf = *(const f16x4*)&Vt[(jd * 16 + l15) * 264 + j * 16 + quad * 4];
      O[jd] = MFMAPV(vf, pf[j], O[jd]);
    }

  __syncthreads();  // #4: all Vt reads done; region becomes transpose tiles

  // ---- epilogue: per-wave 16x72 tile transpose -> coalesced 128B row writes ----
  ushort_t* tile = smem + wave * 1152;  // 16 rows x 72
#pragma unroll
  for (int jd = 0; jd < 4; ++jd)
#pragma unroll
    for (int r = 0; r < 4; ++r)
      tile[l15 * 72 + jd * 16 + quad * 4 + r] = f2bf(O[jd][r] * linv);
  // wave-private: compiler inserts lgkmcnt wait; no barrier needed
#pragma unroll
  for (int g = 0; g < 2; ++g) {
    uint4 w = *(const uint4*)&tile[l15 * 72 + quad * 16 + g * 8];
    *(uint4*)(Yb + gbase + (size_t)(qRow0 + l15) * 1024 + quad * 16 + g * 8) = w;
  }
}

// ---------------- launch ----------------
extern "C" void kernel_launch(void* const* d_in, const int* in_sizes, int n_in,
                              void* d_out, int out_size, void* d_ws, size_t ws_size,
                              hipStream_t stream) {
  (void)in_sizes; (void)n_in; (void)out_size; (void)ws_size;
  const float* x  = (const float*)d_in[0];
  const float* wq = (const float*)d_in[1];
  const float* wk = (const float*)d_in[2];
  const float* wv = (const float*)d_in[3];
  const float* wo = (const float*)d_in[4];

  char* ws = (char*)d_ws;
  // workspace layout (bytes): Xb 16M | Wq..Wo 4x2M | Qb 16M | Kb 16M | Vb 16M | Yb 16M | cs 1M
  ushort_t* Xb  = (ushort_t*)(ws);
  ushort_t* Wqb = (ushort_t*)(ws + 16777216);
  ushort_t* Wkb = Wqb + 1048576;
  ushort_t* Wvb = Wkb + 1048576;
  ushort_t* Wob = Wvb + 1048576;
  ushort_t* Qb  = (ushort_t*)(ws + 25165824);
  ushort_t* Kb  = Qb + 8388608;
  ushort_t* Vb  = Kb + 8388608;
  ushort_t* Yb  = Vb + 8388608;
  float2*   cs  = (float2*)(ws + 92274688);

  prep<<<dim3(12800), dim3(256), 0, stream>>>(x, wq, wk, wv, wo,
                                              Xb, Wqb, Wkb, Wvb, Wob, cs);

  gemm_nt<1><<<dim3(64, 8, 3), dim3(256), 0, stream>>>(
      Xb, Wqb, Wkb, Wvb, (void*)Qb, (void*)Kb, (void*)Vb, 1024, 1024);

  attn<<<dim3(2048), dim3(256), 0, stream>>>(Qb, Kb, Vb, Yb, cs);

  gemm_nt<0><<<dim3(64, 8, 1), dim3(256), 0, stream>>>(
      Yb, Wob, Wob, Wob, d_out, d_out, d_out, 1024, 1024);
}

// Round 7
// 218.287 us; speedup vs baseline: 1.1368x; 1.0549x over previous
//
#include <hip/hip_runtime.h>
#include <math.h>

// ---------------- types / helpers ----------------
typedef float f32x4 __attribute__((ext_vector_type(4)));
typedef __bf16 bf16x8 __attribute__((ext_vector_type(8)));
typedef _Float16 f16x4 __attribute__((ext_vector_type(4)));
typedef unsigned short u16x8 __attribute__((ext_vector_type(8)));
typedef unsigned short ushort_t;

#define MFMA16(a, b, c) __builtin_amdgcn_mfma_f32_16x16x32_bf16((a), (b), (c), 0, 0, 0)
#define MFMAPV(a, b, c) __builtin_amdgcn_mfma_f32_16x16x16f16((a), (b), (c), 0, 0, 0)

static __device__ __forceinline__ ushort_t f2bf(float f) {
  union { float f; unsigned u; } v; v.f = f;
  unsigned u = v.u;
  return (ushort_t)((u + 0x7FFFu + ((u >> 16) & 1u)) >> 16);  // RNE
}
static __device__ __forceinline__ float bf2f(ushort_t h) {
  union { unsigned u; float f; } v; v.u = ((unsigned)h) << 16;
  return v.f;
}
static __device__ __forceinline__ ushort_t f2h_bits(float f) {
  union { _Float16 h; ushort_t u; } v;
  v.h = (_Float16)f;
  return v.u;
}
// async global->LDS, 16B per lane; lds dest = wave-uniform base + lane*16
static __device__ __forceinline__ void gl_lds16(const void* g, void* lds_uniform) {
  __builtin_amdgcn_global_load_lds(
      (const __attribute__((address_space(1))) unsigned int*)g,
      (__attribute__((address_space(3))) unsigned int*)lds_uniform, 16, 0, 0);
}

// ---------------- fused prep: RoPE table + casts ----------
__global__ void prep(const float* __restrict__ x,
                     const float* __restrict__ wq, const float* __restrict__ wk,
                     const float* __restrict__ wv, const float* __restrict__ wo,
                     ushort_t* __restrict__ Xb, ushort_t* __restrict__ Wqb,
                     ushort_t* __restrict__ Wkb, ushort_t* __restrict__ Wvb,
                     ushort_t* __restrict__ Wob, float2* __restrict__ cs) {
  const int bid = blockIdx.x;
  if (bid < 512) {
    int idx = bid * 256 + threadIdx.x;  // 4096*32 entries
    int pos = idx >> 5, i = idx & 31;
    double inv = exp2(-(double)i * 0.41524101186092029);  // log2(10000)/32
    double th = (double)pos * inv;
    double s, c;
    sincos(th, &s, &c);
    cs[idx] = make_float2((float)c, (float)s);
  } else {
    const float* src;
    ushort_t* dst;
    int i;
    if (bid < 8704) {
      src = x; dst = Xb;
      i = (bid - 512) * 256 + threadIdx.x;
    } else {
      const int wi = (bid - 8704) >> 10;
      src = (wi == 0) ? wq : (wi == 1) ? wk : (wi == 2) ? wv : wo;
      dst = (wi == 0) ? Wqb : (wi == 1) ? Wkb : (wi == 2) ? Wvb : Wob;
      i = ((bid - 8704) & 1023) * 256 + threadIdx.x;
    }
    f32x4 v = ((const f32x4*)src)[i];
    ushort4 o;
    o.x = f2bf(v.x); o.y = f2bf(v.y); o.z = f2bf(v.z); o.w = f2bf(v.w);
    ((ushort4*)dst)[i] = o;
  }
}

// ---------------- shared NT GEMM core, BK=64, XOR-swizzled LDS ----------------
// C[m][n] = sum_k A[m][k]*W[n][k]. Tile 128 x NB. OUTBF: 1=bf16 out, 0=f32 out.
template <int OUTBF, int NB>
static __device__ __forceinline__ void gemm_core(
    ushort_t* __restrict__ As, ushort_t* __restrict__ Bs,
    const ushort_t* __restrict__ A, const ushort_t* __restrict__ W,
    void* __restrict__ Cv, int K, int N, int bm, int bn) {
  constexpr int JN = NB / 32;  // col-frags per wave: 4 (NB=128) or 2 (NB=64)
  const int t = threadIdx.x;
  const int lane = t & 63;
  const int l15 = lane & 15;
  const int quad = lane >> 4;
  const int wave = t >> 6;
  const int wm = wave & 1, wn = wave >> 1;

  const int srow = t >> 3;
  const int schunk = (t & 7) ^ (srow & 7);
  const ushort_t* Ag = A + (size_t)(bm * 128 + srow) * K + schunk * 8;
  const ushort_t* Wg = W + (size_t)(bn * NB + srow) * K + schunk * 8;
  char* AsB = (char*)As + (t & 192) * 16;  // wave-uniform; lane slot = base + lane*16
  char* BsB = (char*)Bs + (t & 192) * 16;
  const size_t rK = (size_t)32 * K;

  const f32x4 zero4 = {0.f, 0.f, 0.f, 0.f};
  f32x4 acc[4][JN];
#pragma unroll
  for (int i = 0; i < 4; ++i)
#pragma unroll
    for (int j = 0; j < JN; ++j) acc[i][j] = zero4;

  for (int kt = 0; kt < K; kt += 64) {
#pragma unroll
    for (int p = 0; p < 4; ++p) gl_lds16(Ag + p * rK + kt, AsB + p * 4096);
#pragma unroll
    for (int p = 0; p < NB / 32; ++p) gl_lds16(Wg + p * rK + kt, BsB + p * 4096);
    __syncthreads();
#pragma unroll
    for (int ks = 0; ks < 2; ++ks) {
      bf16x8 af[4], bfr[JN];
#pragma unroll
      for (int i = 0; i < 4; ++i) {
        const int r = wm * 64 + i * 16 + l15;
        af[i] = *(const bf16x8*)&As[r * 64 + (((ks * 4 + quad) ^ (r & 7)) * 8)];
      }
#pragma unroll
      for (int j = 0; j < JN; ++j) {
        const int r = wn * (NB / 2) + j * 16 + l15;
        bfr[j] = *(const bf16x8*)&Bs[r * 64 + (((ks * 4 + quad) ^ (r & 7)) * 8)];
      }
#pragma unroll
      for (int i = 0; i < 4; ++i)
#pragma unroll
        for (int j = 0; j < JN; ++j) acc[i][j] = MFMA16(af[i], bfr[j], acc[i][j]);
    }
    __syncthreads();
  }

  const int rbase = bm * 128 + wm * 64 + quad * 4;
  const int cbase = bn * NB + wn * (NB / 2) + l15;
#pragma unroll
  for (int i = 0; i < 4; ++i)
#pragma unroll
    for (int j = 0; j < JN; ++j)
#pragma unroll
      for (int r = 0; r < 4; ++r) {
        size_t idx = (size_t)(rbase + i * 16 + r) * N + (cbase + j * 16);
        if (OUTBF)
          ((ushort_t*)Cv)[idx] = f2bf(acc[i][j][r]);
        else
          ((float*)Cv)[idx] = acc[i][j][r];
      }
}

// QKV: tile 128x128, z selects (W,C). Proven config: 65.7us, VGPR 80.
__global__ __launch_bounds__(256) void gemm_qkv(
    const ushort_t* __restrict__ A,
    const ushort_t* __restrict__ W0, const ushort_t* __restrict__ W1, const ushort_t* __restrict__ W2,
    void* __restrict__ C0, void* __restrict__ C1, void* __restrict__ C2, int K, int N) {
  __shared__ __align__(16) ushort_t As[128 * 64];
  __shared__ __align__(16) ushort_t Bs[128 * 64];
  const int z = blockIdx.z;
  const ushort_t* W = (z == 0) ? W0 : (z == 1 ? W1 : W2);
  void* Cv = (z == 0) ? C0 : (z == 1 ? C1 : C2);
  gemm_core<1, 128>(As, Bs, A, W, Cv, K, N, blockIdx.x, blockIdx.y);
}

// proj: tile 128x64 -> 1024 blocks, LDS 24KB, higher residency (single-generation fix).
__global__ __launch_bounds__(256) void gemm_proj(
    const ushort_t* __restrict__ A, const ushort_t* __restrict__ W,
    float* __restrict__ C, int K, int N) {
  __shared__ __align__(16) ushort_t As[128 * 64];
  __shared__ __align__(16) ushort_t Bs[64 * 64];
  gemm_core<0, 64>(As, Bs, A, W, (void*)C, K, N, blockIdx.x, blockIdx.y);
}

// ---------------- persistent-window fused attention ----------------
// grid 512 = (b,h,win); 256 threads / 4 waves. Block stages K (roped, bf16) and V
// (transposed, fp16) ONCE, then loops 4 q-slices; each wave does 16 q x 256 k per slice.
// S^T = MFMA(A=K, B=Q): C-layout row k=quad*4+r, col q=l15 == f16-MFMA B-operand layout
// -> P frags are a pure register convert; O^T col is q=l15 -> 1/sum folds into epilogue.
// LDS 79,872 B: Ks[256][72] @0 (36,864) | Vt[64][264] @18432u (33,792) | tiles @35328u (9,216).
// One barrier total; 2 blocks/CU, all 512 co-resident.
static __device__ __forceinline__ void rope8(const ushort_t* __restrict__ g,
                                             ushort_t* __restrict__ lds,
                                             const float2* __restrict__ cs4) {
  uint4 raw = *(const uint4*)g;
  unsigned rw[4] = {raw.x, raw.y, raw.z, raw.w};
  ushort_t o[8];
#pragma unroll
  for (int m = 0; m < 4; ++m) {
    float x1 = bf2f((ushort_t)(rw[m] & 0xffffu));
    float x2 = bf2f((ushort_t)(rw[m] >> 16));
    float2 sc = cs4[m];
    o[2 * m]     = f2bf(x1 * sc.x - x2 * sc.y);
    o[2 * m + 1] = f2bf(x1 * sc.y + x2 * sc.x);
  }
  uint4 w;
  w.x = (unsigned)o[0] | ((unsigned)o[1] << 16);
  w.y = (unsigned)o[2] | ((unsigned)o[3] << 16);
  w.z = (unsigned)o[4] | ((unsigned)o[5] << 16);
  w.w = (unsigned)o[6] | ((unsigned)o[7] << 16);
  *(uint4*)lds = w;  // ds_write_b128
}

__global__ __launch_bounds__(256) void attn(
    const ushort_t* __restrict__ Qb, const ushort_t* __restrict__ Kb,
    const ushort_t* __restrict__ Vb, ushort_t* __restrict__ Yb,
    const float2* __restrict__ cs) {
  __shared__ __align__(16) ushort_t smem[39936];  // 79,872 B
  ushort_t* Ks = smem;            // [256][72] bf16, roped
  ushort_t* Vt = smem + 18432;    // [64][264] fp16 bits, transposed
  ushort_t* tiles = smem + 35328; // 4 waves x 16x72 epilogue transpose

  const int t = threadIdx.x;
  const int lane = t & 63, wave = t >> 6;
  const int l15 = lane & 15, quad = lane >> 4;
  const int s = blockIdx.x;
  const int win = s & 15, h = (s >> 4) & 15, b = s >> 8;
  const int kBase = win * 256;
  const size_t gbase = ((size_t)b * 4096) * 1024 + h * 64;

  const int sr = t >> 3;       // 0..31
  const int c0 = (t & 7) * 8;  // 0..56

  // ---- V global loads first (in flight during K rope) ----
  uint4 vraw[8];
#pragma unroll
  for (int p = 0; p < 8; ++p)
    vraw[p] = *(const uint4*)(Vb + gbase + (size_t)(kBase + p * 32 + sr) * 1024 + c0);

  // ---- stage K with rope, padded [256][72] ----
#pragma unroll
  for (int p = 0; p < 8; ++p) {
    int r = p * 32 + sr;
    rope8(Kb + gbase + (size_t)(kBase + r) * 1024 + c0, Ks + r * 72 + c0,
          cs + (kBase + r) * 32 + (c0 >> 1));
  }

  // ---- stage V transposed Vt[d][k] as fp16, lane-staggered stores ----
#pragma unroll
  for (int p = 0; p < 8; ++p) {
    const int k = p * 32 + sr;
    ushort_t vv[8];
    vv[0] = f2h_bits(bf2f((ushort_t)(vraw[p].x & 0xffffu)));
    vv[1] = f2h_bits(bf2f((ushort_t)(vraw[p].x >> 16)));
    vv[2] = f2h_bits(bf2f((ushort_t)(vraw[p].y & 0xffffu)));
    vv[3] = f2h_bits(bf2f((ushort_t)(vraw[p].y >> 16)));
    vv[4] = f2h_bits(bf2f((ushort_t)(vraw[p].z & 0xffffu)));
    vv[5] = f2h_bits(bf2f((ushort_t)(vraw[p].z >> 16)));
    vv[6] = f2h_bits(bf2f((ushort_t)(vraw[p].w & 0xffffu)));
    vv[7] = f2h_bits(bf2f((ushort_t)(vraw[p].w >> 16)));
#pragma unroll
    for (int e = 0; e < 8; ++e) {
      const int ee = (e + (t & 7)) & 7;
      Vt[(c0 + ee) * 264 + k] = vv[ee];
    }
  }
  __syncthreads();  // the ONLY barrier: Ks + Vt staged

  const f32x4 zero4 = {0.f, 0.f, 0.f, 0.f};

  // ---- loop over 4 q-slices; K/V stay resident ----
  for (int qq = 0; qq < 4; ++qq) {
    const int qRow0 = kBase + qq * 64 + wave * 16;

    // Q B-frags from global, roped + scaled in regs (pairs lane-local)
    bf16x8 qf[2];
#pragma unroll
    for (int ks = 0; ks < 2; ++ks) {
      union { u16x8 u; bf16x8 b; } aq;
      aq.u = *(const u16x8*)(Qb + gbase + (size_t)(qRow0 + l15) * 1024 + ks * 32 + quad * 8);
      const float2* csq = cs + (size_t)((qRow0 + l15) & 4095) * 32 + ks * 16 + quad * 4;
#pragma unroll
      for (int m = 0; m < 4; ++m) {
        float x1 = bf2f(aq.u[2 * m]);
        float x2 = bf2f(aq.u[2 * m + 1]);
        float2 sc = csq[m];
        aq.u[2 * m]     = f2bf((x1 * sc.x - x2 * sc.y) * 0.125f);
        aq.u[2 * m + 1] = f2bf((x1 * sc.y + x2 * sc.x) * 0.125f);
      }
      qf[ks] = aq.b;
    }

    // S^T = K·Q^T : rows k = j*16+quad*4+r, col q = l15
    f32x4 S[16];
#pragma unroll
    for (int j = 0; j < 16; ++j) S[j] = zero4;
#pragma unroll
    for (int ks = 0; ks < 2; ++ks)
#pragma unroll
      for (int j = 0; j < 16; ++j) {
        bf16x8 kf = *(const bf16x8*)&Ks[(j * 16 + l15) * 72 + ks * 32 + quad * 8];
        S[j] = MFMA16(kf, qf[ks], S[j]);
      }

    // softmax: one (max,sum) per lane (column q = l15); quads combined via shfl
    float mx = S[0][0];
#pragma unroll
    for (int j = 0; j < 16; ++j)
#pragma unroll
      for (int e = 0; e < 4; ++e) mx = fmaxf(mx, S[j][e]);
    mx = fmaxf(mx, __shfl_xor(mx, 16));
    mx = fmaxf(mx, __shfl_xor(mx, 32));
    float sum = 0.f;
#pragma unroll
    for (int j = 0; j < 16; ++j)
#pragma unroll
      for (int e = 0; e < 4; ++e) {
        float e_ = __expf(S[j][e] - mx);
        S[j][e] = e_;
        sum += e_;
      }
    sum += __shfl_xor(sum, 16);
    sum += __shfl_xor(sum, 32);
    const float linv = 1.0f / sum;

    // P frags: C-layout == f16-MFMA B-operand layout -> pure register cvt
    f16x4 pf[16];
#pragma unroll
    for (int j = 0; j < 16; ++j) pf[j] = __builtin_convertvector(S[j], f16x4);

    // O^T[d][q] = sum_k V^T[d][k] P[q][k] via f16 16x16x16 MFMA
    f32x4 O[4];
#pragma unroll
    for (int jd = 0; jd < 4; ++jd) O[jd] = zero4;
#pragma unroll
    for (int j = 0; j < 16; ++j)
#pragma unroll
      for (int jd = 0; jd < 4; ++jd) {
        f16x4 vf = *(const f16x4*)&Vt[(jd * 16 + l15) * 264 + j * 16 + quad * 4];
        O[jd] = MFMAPV(vf, pf[j], O[jd]);
      }

    // epilogue: per-wave 16x72 tile transpose -> coalesced 128B row writes
    ushort_t* tile = tiles + wave * 1152;
#pragma unroll
    for (int jd = 0; jd < 4; ++jd)
#pragma unroll
      for (int r = 0; r < 4; ++r)
        tile[l15 * 72 + jd * 16 + quad * 4 + r] = f2bf(O[jd][r] * linv);
    // wave-private tile: in-wave LDS ordering + compiler lgkmcnt waits suffice
#pragma unroll
    for (int g = 0; g < 2; ++g) {
      uint4 w = *(const uint4*)&tile[l15 * 72 + quad * 16 + g * 8];
      *(uint4*)(Yb + gbase + (size_t)(qRow0 + l15) * 1024 + quad * 16 + g * 8) = w;
    }
  }
}

// ---------------- launch ----------------
extern "C" void kernel_launch(void* const* d_in, const int* in_sizes, int n_in,
                              void* d_out, int out_size, void* d_ws, size_t ws_size,
                              hipStream_t stream) {
  (void)in_sizes; (void)n_in; (void)out_size; (void)ws_size;
  const float* x  = (const float*)d_in[0];
  const float* wq = (const float*)d_in[1];
  const float* wk = (const float*)d_in[2];
  const float* wv = (const float*)d_in[3];
  const float* wo = (const float*)d_in[4];

  char* ws = (char*)d_ws;
  // workspace layout (bytes): Xb 16M | Wq..Wo 4x2M | Qb 16M | Kb 16M | Vb 16M | Yb 16M | cs 1M
  ushort_t* Xb  = (ushort_t*)(ws);
  ushort_t* Wqb = (ushort_t*)(ws + 16777216);
  ushort_t* Wkb = Wqb + 1048576;
  ushort_t* Wvb = Wkb + 1048576;
  ushort_t* Wob = Wvb + 1048576;
  ushort_t* Qb  = (ushort_t*)(ws + 25165824);
  ushort_t* Kb  = Qb + 8388608;
  ushort_t* Vb  = Kb + 8388608;
  ushort_t* Yb  = Vb + 8388608;
  float2*   cs  = (float2*)(ws + 92274688);

  prep<<<dim3(12800), dim3(256), 0, stream>>>(x, wq, wk, wv, wo,
                                              Xb, Wqb, Wkb, Wvb, Wob, cs);

  gemm_qkv<<<dim3(64, 8, 3), dim3(256), 0, stream>>>(
      Xb, Wqb, Wkb, Wvb, (void*)Qb, (void*)Kb, (void*)Vb, 1024, 1024);

  attn<<<dim3(512), dim3(256), 0, stream>>>(Qb, Kb, Vb, Yb, cs);

  gemm_proj<<<dim3(64, 16), dim3(256), 0, stream>>>(Yb, Wob, (float*)d_out, 1024, 1024);
}